// Round 1
// baseline (357.444 us; speedup 1.0000x reference)
//
#include <hip/hip_runtime.h>

// cdist(x1, x2) on MI355X: d[i][j] = sqrt(||x1_i||^2 + ||x2_j||^2 - 2*x1_i.x2_j)
// Strategy: fp32->bf16 convert + fp32 row norms (prologue), then bf16 MFMA GEMM
// (m97 structure: 128x128 tile, BK=64, global_load_lds width=16) with fused
// sqrt epilogue. Output writes (256 MiB) are the roofline (~43 us @ 6.3 TB/s).

typedef __bf16 v8bf __attribute__((ext_vector_type(8)));
typedef float v4f __attribute__((ext_vector_type(4)));

#define NROWS 8192
#define KDIM  256
#define TILE  128
#define BK    64

typedef const __attribute__((address_space(1))) ushort* gas_ushort_p;
typedef __attribute__((address_space(3))) ushort* las_ushort_p;

__device__ __forceinline__ void async_load16(const ushort* g, ushort* l) {
    // global -> LDS direct DMA, 16B per lane. LDS dest is wave-uniform base +
    // lane*16 (hardware uses first lane's lds address).
    __builtin_amdgcn_global_load_lds((gas_ushort_p)g, (las_ushort_p)l, 16, 0, 0);
}

__device__ __forceinline__ ushort f2bf_rne(float f) {
    union { float f; unsigned u; } a; a.f = f;
    unsigned u = a.u + 0x7fffu + ((a.u >> 16) & 1u);  // round-to-nearest-even
    return (ushort)(u >> 16);
}

// One wave per row: load 256 floats as float4/lane, emit bf16 row + fp32 norm.
__global__ __launch_bounds__(256) void cvt_norm_kernel(
    const float* __restrict__ x, ushort* __restrict__ xb, float* __restrict__ sq) {
    const int wave = threadIdx.x >> 6;
    const int lane = threadIdx.x & 63;
    const int row  = blockIdx.x * 4 + wave;
    const float4 v = ((const float4*)(x + (size_t)row * KDIM))[lane];
    float s = v.x * v.x + v.y * v.y + v.z * v.z + v.w * v.w;
#pragma unroll
    for (int off = 32; off; off >>= 1) s += __shfl_down(s, off);
    if (lane == 0) sq[row] = s;
    ushort4 o;
    o.x = f2bf_rne(v.x); o.y = f2bf_rne(v.y);
    o.z = f2bf_rne(v.z); o.w = f2bf_rne(v.w);
    ((ushort4*)(xb + (size_t)row * KDIM))[lane] = o;
}

__global__ __launch_bounds__(256) void cdist_mfma_kernel(
    const ushort* __restrict__ A,    // x1 bf16, [8192][256]
    const ushort* __restrict__ B,    // x2 bf16, [8192][256]
    const float* __restrict__ sq1,   // ||x1_i||^2
    const float* __restrict__ sq2,   // ||x2_j||^2
    float* __restrict__ out) {       // [8192][8192]
    __shared__ ushort As[TILE * BK];  // 16 KiB, row-major, NO padding
    __shared__ ushort Bs[TILE * BK];  // (global_load_lds needs contiguous lanes)

    const int bm = blockIdx.x, bn = blockIdx.y;
    const int tid  = threadIdx.x;
    const int wave = tid >> 6;
    const int lane = tid & 63;
    const int wr = wave >> 1;         // wave tile row (0..1) -> 64 rows
    const int wc = wave & 1;          // wave tile col (0..1) -> 64 cols

    // staging lane layout: 8 lanes x 16B cover one 64-elem bf16 row (128 B)
    const int lrow = lane >> 3;       // 0..7 rows within an 8-row chunk
    const int lk   = (lane & 7) * 8;  // bf16 k-offset within row

    v4f acc[4][4];
#pragma unroll
    for (int i = 0; i < 4; ++i)
#pragma unroll
        for (int j = 0; j < 4; ++j) acc[i][j] = (v4f){0.f, 0.f, 0.f, 0.f};

    const int half = lane >> 4;       // 0..3
    const int mrow = lane & 15;       // fragment row/col within 16

    for (int kt = 0; kt < KDIM; kt += BK) {
        __syncthreads();  // previous tile's LDS reads done before overwrite
#pragma unroll
        for (int c = 0; c < 4; ++c) {
            const int rbase = wave * 32 + c * 8;   // 8 rows per wave-call
            const ushort* ga =
                A + (size_t)(bm * TILE + rbase + lrow) * KDIM + kt + lk;
            const ushort* gb =
                B + (size_t)(bn * TILE + rbase + lrow) * KDIM + kt + lk;
            async_load16(ga, &As[rbase * BK]);
            async_load16(gb, &Bs[rbase * BK]);
        }
        __syncthreads();  // drains vmcnt before barrier (compiler-inserted)
#pragma unroll
        for (int kk = 0; kk < BK; kk += 32) {
            v8bf a[4], b[4];
#pragma unroll
            for (int i = 0; i < 4; ++i) {
                a[i] = *(const v8bf*)&As[(wr * 64 + i * 16 + mrow) * BK + kk + half * 8];
                b[i] = *(const v8bf*)&Bs[(wc * 64 + i * 16 + mrow) * BK + kk + half * 8];
            }
#pragma unroll
            for (int i = 0; i < 4; ++i)
#pragma unroll
                for (int j = 0; j < 4; ++j)
                    acc[i][j] = __builtin_amdgcn_mfma_f32_16x16x32_bf16(
                        a[i], b[j], acc[i][j], 0, 0, 0);
        }
    }

    // Epilogue: C/D layout col=lane&15, row=(lane>>4)*4+reg (m89/m91 verified)
    const int m0 = bm * TILE + wr * 64;
    const int n0 = bn * TILE + wc * 64;
#pragma unroll
    for (int j = 0; j < 4; ++j) {
        const int col = n0 + j * 16 + mrow;
        const float s2 = sq2[col];
#pragma unroll
        for (int i = 0; i < 4; ++i) {
#pragma unroll
            for (int r = 0; r < 4; ++r) {
                const int row = m0 + i * 16 + half * 4 + r;
                const float d2 = sq1[row] + s2 - 2.0f * acc[i][j][r];
                out[(size_t)row * NROWS + col] = sqrtf(fmaxf(d2, 0.0f));
            }
        }
    }
}

extern "C" void kernel_launch(void* const* d_in, const int* in_sizes, int n_in,
                              void* d_out, int out_size, void* d_ws, size_t ws_size,
                              hipStream_t stream) {
    const float* x1 = (const float*)d_in[0];
    const float* x2 = (const float*)d_in[1];
    float* out = (float*)d_out;

    // ws layout: A_bf16 (4 MiB) | B_bf16 (4 MiB) | sq1 (32 KiB) | sq2 (32 KiB)
    ushort* Ab = (ushort*)d_ws;
    ushort* Bb = Ab + (size_t)NROWS * KDIM;
    float* sq1 = (float*)(Bb + (size_t)NROWS * KDIM);
    float* sq2 = sq1 + NROWS;

    cvt_norm_kernel<<<NROWS / 4, 256, 0, stream>>>(x1, Ab, sq1);
    cvt_norm_kernel<<<NROWS / 4, 256, 0, stream>>>(x2, Bb, sq2);

    dim3 grid(NROWS / TILE, NROWS / TILE);  // 64 x 64
    cdist_mfma_kernel<<<grid, 256, 0, stream>>>(Ab, Bb, sq1, sq2, out);
}